// Round 24
// baseline (186.727 us; speedup 1.0000x reference)
//
#include <hip/hip_runtime.h>
#include <math.h>

#define B_ 4
#define S_ 2048
#define E_ 1024
#define H_ 16
#define D_ 64
#define M_ (B_*S_)
// 1/sqrt(2048) * log2(e): scale folded into Wq/bq so softmax uses exp2 directly
#define QSCALE (0.022097086912079608f * 1.4426950408889634f)

typedef __bf16 bf16_t;
typedef __bf16 bf16x8 __attribute__((ext_vector_type(8)));
typedef float  f32x4  __attribute__((ext_vector_type(4)));

// async global->LDS, 16B per lane. LDS dest must be linear (base + lane*16).
__device__ __forceinline__ void gload_lds16(const void* g, void* l) {
    __builtin_amdgcn_global_load_lds(
        (const __attribute__((address_space(1))) void*)g,
        (__attribute__((address_space(3))) void*)l, 16, 0, 0);
}
__device__ __forceinline__ bf16x8 ldsx8(const void* p) {
    return __builtin_bit_cast(bf16x8, *(const uint4*)p);
}
__device__ __forceinline__ unsigned short bf16bits(float x) {
    return __builtin_bit_cast(unsigned short, (bf16_t)x);
}
// counted waitcnt: allow N newest vector-mem ops to stay in flight
template<int N> __device__ __forceinline__ void waitv() {
    if constexpr (N == 8)      asm volatile("s_waitcnt vmcnt(8) lgkmcnt(0)" ::: "memory");
    else if constexpr (N == 4) asm volatile("s_waitcnt vmcnt(4) lgkmcnt(0)" ::: "memory");
    else if constexpr (N == 3) asm volatile("s_waitcnt vmcnt(3) lgkmcnt(0)" ::: "memory");
    else if constexpr (N == 2) asm volatile("s_waitcnt vmcnt(2) lgkmcnt(0)" ::: "memory");
    else                       asm volatile("s_waitcnt vmcnt(0) lgkmcnt(0)" ::: "memory");
}
// swizzle for K-tile QK^T A-frag read rows {32c + 8a + 4kf + b}: f = (b + 2a) & 7
__device__ __forceinline__ int fk(int row) { return ((row & 3) + 2 * ((row >> 3) & 3)) & 7; }

// ---------------------------------------------------------------------------
// bf16 MFMA GEMM, C = A[M,K] x Bt[N,K]^T. BK=64.
// MODE 0: dbuf + counted-vmcnt; bf16 out + bias.
// MODE 2: compacted KV projection; single-buffer 32KB (one residency wave);
//         supertile alive-block mapping; K -> ob1[b][ci][nn], V -> ob2[bh][d][ci].
// MODE 4: MODE 0 + per-row LN stats (sum, sumsq of post-bias values) via
//         shfl-reduce + atomicAdd into st1/st2.
// MODE 6: LN1-fused FFN1: u = rstd*(A@W1g - mean*cs) + bb, exact GELU, bf16.
//         bias0 = cs, bias1 = bb; st1/st2 = row sum/sumsq (read).
// ---------------------------------------------------------------------------
template<int BM, int BN, int MODE>
__global__ __launch_bounds__(256) void gemm_bf16(
    const bf16_t* __restrict__ A, const bf16_t* __restrict__ Bt,
    bf16_t* __restrict__ ob0, bf16_t* __restrict__ ob1, bf16_t* __restrict__ ob2,
    const float* __restrict__ bias0, const float* __restrict__ bias1,
    float* __restrict__ st1, float* __restrict__ st2,
    const int* __restrict__ sidx, const int* __restrict__ nkv,
    const int* __restrict__ bmap,
    int M, int N, int K)
{
    constexpr int FM = BM / 32, FN = BN / 32;
    constexpr int NL = BM / 32 + BN / 32;    // gload_lds per thread per K-step
    constexpr int NBUF = (MODE == 2) ? 1 : 2;
    __shared__ bf16_t As[NBUF][BM * 64];
    __shared__ bf16_t Bs[NBUF][BN * 64];

    const int tid = threadIdx.x;
    const int w   = tid >> 6;
    const int wr  = w >> 1, wc = w & 1;
    const int lr  = tid & 15;
    const int lg  = (tid >> 4) & 3;

    int bm, bn;
    if constexpr (MODE == 2) {
        const int flat = blockIdx.y * gridDim.x + blockIdx.x;   // [0,1024)
        const int nab = nkv[4];
        const int st = flat >> 7, wfl = flat & 127;
        const int ab = st * 8 + (wfl & 7);
        if (ab >= nab) return;
        const int col = wfl >> 3;
        const int ent = bmap[ab];
        bm = ((ent >> 8) << 11) + (ent & 255) * BM;   // [b][ci] row base
        bn = col * BN;
    } else {
        // XCD-bijective block swizzle: 8 contiguous chunks, one per XCD
        const int nwg = gridDim.x * gridDim.y;
        int bidf = blockIdx.y * gridDim.x + blockIdx.x;
        bidf = (bidf & 7) * (nwg >> 3) + (bidf >> 3);
        bm = (bidf / gridDim.x) * BM;
        bn = (bidf % gridDim.x) * BN;
    }

    // A-row mapping (MODE 2: gathered via sidx)
    int arow[FM];
    if constexpr (MODE == 2) {
        const int b2 = bm >> 11, rbase = bm & 2047;
        #pragma unroll
        for (int i = 0; i < FM; ++i) {
            const int row = (i * 256 + tid) >> 3;
            arow[i] = (b2 << 11) + sidx[(b2 << 11) + rbase + row];
        }
    } else {
        #pragma unroll
        for (int i = 0; i < FM; ++i)
            arow[i] = bm + ((i * 256 + tid) >> 3);
    }

    f32x4 acc[FM][FN] = {};

    auto STAGE = [&](int buf, int kk) {
        #pragma unroll
        for (int i = 0; i < BM / 32; ++i) {
            int idx = i * 256 + tid;
            int row = idx >> 3, slot = idx & 7;
            gload_lds16(A + (size_t)arow[i] * K + kk + (slot ^ (row & 7)) * 8,
                        (char*)As[buf] + idx * 16);
        }
        #pragma unroll
        for (int i = 0; i < BN / 32; ++i) {
            int idx = i * 256 + tid;
            int row = idx >> 3, slot = idx & 7;
            gload_lds16(Bt + (size_t)(bn + row) * K + kk + (slot ^ (row & 7)) * 8,
                        (char*)Bs[buf] + idx * 16);
        }
    };

    auto COMPUTE = [&](int buf) {
        #pragma unroll
        for (int h = 0; h < 2; ++h) {
            bf16x8 af[FM], bfr[FN];
            #pragma unroll
            for (int m = 0; m < FM; ++m) {
                int row = wr * (BM / 2) + m * 16 + lr;
                af[m] = ldsx8((char*)As[buf] + row * 128 + (((4 * h + lg) ^ (row & 7)) << 4));
            }
            #pragma unroll
            for (int n = 0; n < FN; ++n) {
                int col = wc * (BN / 2) + n * 16 + lr;
                bfr[n] = ldsx8((char*)Bs[buf] + col * 128 + (((4 * h + lg) ^ (col & 7)) << 4));
            }
            #pragma unroll
            for (int m = 0; m < FM; ++m)
                #pragma unroll
                for (int n = 0; n < FN; ++n)
                    acc[m][n] = __builtin_amdgcn_mfma_f32_16x16x32_bf16(
                        af[m], bfr[n], acc[m][n], 0, 0, 0);
        }
    };

    if constexpr (NBUF == 1) {
        for (int kk = 0; kk < K; kk += 64) {
            __syncthreads();
            STAGE(0, kk);
            __syncthreads();
            COMPUTE(0);
        }
    } else {
        STAGE(0, 0);
        int cur = 0;
        for (int kk = 0; kk < K; kk += 64) {
            if (kk + 64 < K) {
                STAGE(cur ^ 1, kk + 64);
                waitv<NL>();
            } else {
                waitv<0>();
            }
            __builtin_amdgcn_s_barrier();
            COMPUTE(cur);
            __builtin_amdgcn_s_barrier();
            cur ^= 1;
        }
    }

    if constexpr (MODE == 2) {
        #pragma unroll
        for (int n = 0; n < FN; ++n) {
            const int gcol = bn + wc * (BN / 2) + n * 16 + lr;
            const int p = gcol >> 10, nn = gcol & 1023;
            const int b2 = bm >> 11;
            const float bvl = p ? bias1[nn] : bias0[nn];
            #pragma unroll
            for (int m = 0; m < FM; ++m) {
                const int ci0 = (bm & 2047) + wr * (BM / 2) + m * 16 + lg * 4;
                if (p) {    // V^T: vtc[((b*1024 + nn) << 11) + ci], 4 consecutive ci
                    ushort4 o;
                    o.x = bf16bits(acc[m][n][0] + bvl);
                    o.y = bf16bits(acc[m][n][1] + bvl);
                    o.z = bf16bits(acc[m][n][2] + bvl);
                    o.w = bf16bits(acc[m][n][3] + bvl);
                    *(ushort4*)(ob2 + ((((size_t)b2 << 10) + nn) << 11) + ci0) = o;
                } else {    // K: kbuf[((b<<11) + ci) << 10 + nn]
                    #pragma unroll
                    for (int r = 0; r < 4; ++r)
                        ob1[((size_t)((b2 << 11) + ci0 + r) << 10) + nn] =
                            (bf16_t)(acc[m][n][r] + bvl);
                }
            }
        }
    } else if constexpr (MODE == 6) {
        // LN1-fused FFN1 epilogue
        #pragma unroll
        for (int n = 0; n < FN; ++n) {
            const int gcol = bn + wc * (BN / 2) + n * 16 + lr;
            const float csn = bias0[gcol], bbn = bias1[gcol];
            #pragma unroll
            for (int m = 0; m < FM; ++m)
                #pragma unroll
                for (int r = 0; r < 4; ++r) {
                    const int grow = bm + wr * (BM / 2) + m * 16 + lg * 4 + r;
                    const float s  = st1[grow];
                    const float sq = st2[grow];
                    const float mean = s * (1.0f / 1024.0f);
                    const float var  = sq * (1.0f / 1024.0f) - mean * mean;
                    const float rstd = rsqrtf(var + 1e-5f);
                    float u = rstd * (acc[m][n][r] - mean * csn) + bbn;
                    u = 0.5f * u * (1.0f + erff(u * 0.70710678118654752f));
                    ob0[(size_t)grow * N + gcol] = (bf16_t)u;
                }
        }
    } else {
        float rs[FM][4], rq[FM][4];
        if constexpr (MODE == 4) {
            #pragma unroll
            for (int m = 0; m < FM; ++m)
                #pragma unroll
                for (int r = 0; r < 4; ++r) { rs[m][r] = 0.0f; rq[m][r] = 0.0f; }
        }
        #pragma unroll
        for (int n = 0; n < FN; ++n) {
            const int gcol = bn + wc * (BN / 2) + n * 16 + lr;
            const float bvl = bias0[gcol];
            #pragma unroll
            for (int m = 0; m < FM; ++m)
                #pragma unroll
                for (int r = 0; r < 4; ++r) {
                    const int grow = bm + wr * (BM / 2) + m * 16 + lg * 4 + r;
                    float v = acc[m][n][r] + bvl;
                    ob0[(size_t)grow * N + gcol] = (bf16_t)v;
                    if constexpr (MODE == 4) {
                        rs[m][r] += v;
                        rq[m][r] += v * v;
                    }
                }
        }
        if constexpr (MODE == 4) {
            // reduce over the 16 lr lanes (xor of lane bits 0..3 stays in lg group)
            #pragma unroll
            for (int m = 0; m < FM; ++m)
                #pragma unroll
                for (int r = 0; r < 4; ++r) {
                    float s = rs[m][r], q = rq[m][r];
                    s += __shfl_xor(s, 1);  q += __shfl_xor(q, 1);
                    s += __shfl_xor(s, 2);  q += __shfl_xor(q, 2);
                    s += __shfl_xor(s, 4);  q += __shfl_xor(q, 4);
                    s += __shfl_xor(s, 8);  q += __shfl_xor(q, 8);
                    if (lr == 0) {
                        const int grow = bm + wr * (BM / 2) + m * 16 + lg * 4 + r;
                        atomicAdd(&st1[grow], s);
                        atomicAdd(&st2[grow], q);
                    }
                }
        }
    }
}

// ---------------------------------------------------------------------------
// Mask compaction (single block): scan -> sidx (pad 0 to 128-mult); nkv[b];
// bmap[ab] = (b<<8)|rb for alive 128-row blocks; nkv[4] = nab.
// ---------------------------------------------------------------------------
__global__ __launch_bounds__(256) void compact_mask(
    const int* __restrict__ mask, int* __restrict__ sidx, int* __restrict__ nkv,
    int* __restrict__ bmap)
{
    __shared__ int wsum[4];
    __shared__ int nkp_s[4];
    const int tid = threadIdx.x;
    const int lane = tid & 63, wv = tid >> 6;
    const int base = tid * 8;

    for (int b = 0; b < 4; ++b) {
        int m[8], loc[8];
        int cnt = 0;
        #pragma unroll
        for (int j = 0; j < 8; ++j) {
            m[j] = mask[b * S_ + base + j];
            loc[j] = cnt;
            cnt += (m[j] != 0);
        }
        int incl = cnt;
        #pragma unroll
        for (int off = 1; off < 64; off <<= 1) {
            int t = __shfl_up(incl, off);
            if (lane >= off) incl += t;
        }
        if (lane == 63) wsum[wv] = incl;
        const int excl_lane = incl - cnt;
        __syncthreads();
        int wbase = 0;
        for (int i = 0; i < wv; ++i) wbase += wsum[i];
        const int total = wsum[0] + wsum[1] + wsum[2] + wsum[3];
        if (tid == 0) { nkv[b] = total; nkp_s[b] = (total + 127) & ~127; }
        const int tbase = wbase + excl_lane;
        #pragma unroll
        for (int j = 0; j < 8; ++j)
            if (m[j]) sidx[b * S_ + tbase + loc[j]] = base + j;
        const int nkp = (total + 127) & ~127;
        for (int c = total + tid; c < nkp; c += 256)
            sidx[b * S_ + c] = 0;
        __syncthreads();
    }

    if (tid == 0) {
        int idx = 0;
        for (int b = 0; b < 4; ++b)
            for (int rb = 0; rb < (nkp_s[b] >> 7); ++rb)
                bmap[idx++] = (b << 8) | rb;
        nkv[4] = idx;
    }
}

// ---------------------------------------------------------------------------
// MFMA flash attention over COMPACTED keys. 8 waves x 32 q-rows = QBLK 256,
// grid 512. Counted-vmcnt dbuf; zero-shuffle P; mask-as-C-init; L via
// ones-row MFMA; exp2-domain scores. 8 bh per XCD.
// ---------------------------------------------------------------------------
__global__ __launch_bounds__(512) void attn_mfma(
    const bf16_t* __restrict__ qg, const bf16_t* __restrict__ kg,
    const bf16_t* __restrict__ vg, const int* __restrict__ nkv,
    bf16_t* __restrict__ ctx)
{
    __shared__ bf16_t ks[2][64 * 64];   // [key][d] 128B rows, fk-swizzled
    __shared__ bf16_t vts[2][64 * 64];  // [d][key] 128B rows, row&7-swizzled

    const int tid = threadIdx.x;
    const int w   = tid >> 6;            // 8 waves
    const int lr  = tid & 15;
    const int lg  = (tid >> 4) & 3;

    const int bid = blockIdx.x;
    const int xcd = bid & 7, kidx = bid >> 3;        // kidx in [0,64)
    const int bh  = xcd * 8 + (kidx >> 3);           // 8 bh per XCD
    const int xq  = kidx & 7;                        // 8 q-blocks of 256
    const int b   = bh >> 4, h = bh & 15;
    const int q0w = xq * 256 + w * 32;               // wave owns 32 q-rows

    const int nk = nkv[b];
    const int ntiles = (nk + 63) >> 6;
    const bool hastail = (nk & 63) != 0;

    bf16x8 aq[2][2];
    #pragma unroll
    for (int f = 0; f < 2; ++f) {
        const bf16_t* qp = qg + ((size_t)(b * S_ + q0w + f * 16 + lr) << 10) + h * 64 + lg * 8;
        aq[f][0] = ldsx8(qp);
        aq[f][1] = ldsx8(qp + 32);
    }

    bf16x8 onesf;
    {
        bf16_t o1 = (bf16_t)((lr == 0) ? 1.0f : 0.0f);
        #pragma unroll
        for (int j = 0; j < 8; ++j) onesf[j] = o1;
    }

    int koff[2][2][2], voff[2][4];
    #pragma unroll
    for (int c = 0; c < 2; ++c) {
        #pragma unroll
        for (int kf1 = 0; kf1 < 2; ++kf1) {
            const int row = c * 32 + 8 * (lr >> 2) + 4 * kf1 + (lr & 3);
            const int f = fk(row);
            koff[c][kf1][0] = row * 128 + ((lg ^ f) << 4);
            koff[c][kf1][1] = row * 128 + (((4 + lg) ^ f) << 4);
        }
        #pragma unroll
        for (int n = 0; n < 4; ++n) {
            const int rowv = n * 16 + lr;
            voff[c][n] = rowv * 128 + (((4 * c + lg) ^ (rowv & 7)) << 4);
        }
    }

    const int srow = tid >> 3, sslot = tid & 7;      // srow in [0,64)
    const bf16_t* kptr = kg + ((size_t)((b << 11) + srow) << 10) + h * 64
                            + (sslot ^ fk(srow)) * 8;
    const bf16_t* vptr = vg + (((size_t)bh * 64 + srow) << 11)
                            + (sslot ^ (srow & 7)) * 8;
    char* kdst = (char*)ks + tid * 16;
    char* vdst = (char*)vts + tid * 16;

    f32x4 accO[2][4] = {};
    f32x4 accL[2] = {};

    auto STAGE = [&](int buf) {
        const int nb = buf << 13;
        gload_lds16(kptr, kdst + nb);
        gload_lds16(vptr, vdst + nb);
        kptr += (size_t)64 << 10;
        vptr += 64;
    };

    auto COMPUTE = [&](int buf, int t0, bool tl) {
        const char* ksb = (const char*)ks + (buf << 13);
        const char* vsb = (const char*)vts + (buf << 13);
        #pragma unroll
        for (int c = 0; c < 2; ++c) {
            unsigned int pw0[4], pw1[4];
            #pragma unroll
            for (int kf1 = 0; kf1 < 2; ++kf1) {
                bf16x8 a0 = ldsx8(ksb + koff[c][kf1][0]);
                bf16x8 a1 = ldsx8(ksb + koff[c][kf1][1]);
                f32x4 z0 = {}, z1 = {};
                if (tl) {
                    const int keyb = t0 + c * 32 + 8 * lg + 4 * kf1;
                    f32x4 bias;
                    #pragma unroll
                    for (int r = 0; r < 4; ++r)
                        bias[r] = (keyb + r < nk) ? 0.0f : -1.0e9f;
                    z0 = bias; z1 = bias;
                }
                __builtin_amdgcn_s_setprio(1);
                z0 = __builtin_amdgcn_mfma_f32_16x16x32_bf16(a0, aq[0][0], z0, 0, 0, 0);
                z0 = __builtin_amdgcn_mfma_f32_16x16x32_bf16(a1, aq[0][1], z0, 0, 0, 0);
                z1 = __builtin_amdgcn_mfma_f32_16x16x32_bf16(a0, aq[1][0], z1, 0, 0, 0);
                z1 = __builtin_amdgcn_mfma_f32_16x16x32_bf16(a1, aq[1][1], z1, 0, 0, 0);
                __builtin_amdgcn_s_setprio(0);
                const float p00 = __builtin_amdgcn_exp2f(z0[0]);
                const float p01 = __builtin_amdgcn_exp2f(z0[1]);
                const float p02 = __builtin_amdgcn_exp2f(z0[2]);
                const float p03 = __builtin_amdgcn_exp2f(z0[3]);
                const float p10 = __builtin_amdgcn_exp2f(z1[0]);
                const float p11 = __builtin_amdgcn_exp2f(z1[1]);
                const float p12 = __builtin_amdgcn_exp2f(z1[2]);
                const float p13 = __builtin_amdgcn_exp2f(z1[3]);
                pw0[2 * kf1]     = bf16bits(p00) | ((unsigned)bf16bits(p01) << 16);
                pw0[2 * kf1 + 1] = bf16bits(p02) | ((unsigned)bf16bits(p03) << 16);
                pw1[2 * kf1]     = bf16bits(p10) | ((unsigned)bf16bits(p11) << 16);
                pw1[2 * kf1 + 1] = bf16bits(p12) | ((unsigned)bf16bits(p13) << 16);
            }
            uint4 pk0 = {pw0[0], pw0[1], pw0[2], pw0[3]};
            uint4 pk1 = {pw1[0], pw1[1], pw1[2], pw1[3]};
            const bf16x8 pa0 = __builtin_bit_cast(bf16x8, pk0);
            const bf16x8 pa1 = __builtin_bit_cast(bf16x8, pk1);

            __builtin_amdgcn_s_setprio(1);
            #pragma unroll
            for (int n = 0; n < 4; ++n) {
                bf16x8 av = ldsx8(vsb + voff[c][n]);
                accO[0][n] = __builtin_amdgcn_mfma_f32_16x16x32_bf16(av, pa0, accO[0][n], 0, 0, 0);
                accO[1][n] = __builtin_amdgcn_mfma_f32_16x16x32_bf16(av, pa1, accO[1][n], 0, 0, 0);
            }
            accL[0] = __builtin_amdgcn_mfma_f32_16x16x32_bf16(onesf, pa0, accL[0], 0, 0, 0);
            accL[1] = __builtin_amdgcn_mfma_f32_16x16x32_bf16(onesf, pa1, accL[1], 0, 0, 0);
            __builtin_amdgcn_s_setprio(0);
        }
    };

    STAGE(0);
    int cur = 0;
    for (int t = 0; t < ntiles; ++t) {
        if (t + 1 < ntiles) {
            STAGE(cur ^ 1);
            waitv<2>();
        } else {
            waitv<0>();
        }
        __builtin_amdgcn_s_barrier();
        COMPUTE(cur, t * 64, hastail && (t == ntiles - 1));
        __builtin_amdgcn_s_barrier();
        cur ^= 1;
    }

    #pragma unroll
    for (int f = 0; f < 2; ++f) {
        const float inv = 1.0f / __shfl(accL[f][0], lr);
        bf16_t* obase = ctx + ((size_t)(b * S_ + q0w + f * 16 + lr) << 10) + h * 64;
        #pragma unroll
        for (int n = 0; n < 4; ++n) {
            ushort4 o;
            o.x = bf16bits(accO[f][n][0] * inv);
            o.y = bf16bits(accO[f][n][1] * inv);
            o.z = bf16bits(accO[f][n][2] * inv);
            o.w = bf16bits(accO[f][n][3] * inv);
            *(ushort4*)(obase + n * 16 + lg * 4) = o;
        }
    }
}

// ---------------------------------------------------------------------------
// Fused prep: x cast + weight transposes (g1 folded into W1) + bqs + cs/bb
// + zero LN1 stats accumulators (replay-safe).
// ---------------------------------------------------------------------------
__global__ __launch_bounds__(256) void prep_all(
    const float* __restrict__ x, bf16_t* __restrict__ xb,
    const float* __restrict__ Wq, const float* __restrict__ Wk,
    const float* __restrict__ Wv, bf16_t* __restrict__ WqkvT,
    const float* __restrict__ Wo, bf16_t* __restrict__ WoT,
    const float* __restrict__ W1, bf16_t* __restrict__ W1gT,
    const float* __restrict__ W2, bf16_t* __restrict__ W2T,
    const float* __restrict__ bq, float* __restrict__ bqs,
    const float* __restrict__ g1, const float* __restrict__ b1,
    const float* __restrict__ c1,
    float* __restrict__ csv, float* __restrict__ bbv,
    float* __restrict__ s1, float* __restrict__ sq1)
{
    __shared__ float t[32][33];
    __shared__ float red[2][4][64];
    const int tid = threadIdx.x;
    int bid = blockIdx.x;

    if (bid < 4096) {               // x f32 -> bf16, 8 per thread
        int i = bid * 256 + tid;
        float4 a = ((const float4*)x)[i * 2];
        float4 b = ((const float4*)x)[i * 2 + 1];
        unsigned int p0 = bf16bits(a.x) | ((unsigned)bf16bits(a.y) << 16);
        unsigned int p1 = bf16bits(a.z) | ((unsigned)bf16bits(a.w) << 16);
        unsigned int p2 = bf16bits(b.x) | ((unsigned)bf16bits(b.y) << 16);
        unsigned int p3 = bf16bits(b.z) | ((unsigned)bf16bits(b.w) << 16);
        uint4 o = {p0, p1, p2, p3};
        ((uint4*)xb)[i] = o;
        return;
    }
    bid -= 4096;

    if (bid == 4224) {              // bqs = bq * QSCALE
        #pragma unroll
        for (int j = 0; j < 4; ++j)
            bqs[tid * 4 + j] = bq[tid * 4 + j] * QSCALE;
        return;
    }
    if (bid == 4225) {              // cs / bb reduction (R9-validated)
        const int n = tid & 63, part = tid >> 6;
        float csp = 0.0f, bbp = 0.0f;
        for (int k = part * 256; k < part * 256 + 256; ++k) {
            const float wv = W1[k * 64 + n];
            csp += g1[k] * wv;
            bbp += b1[k] * wv;
        }
        red[0][part][n] = csp;
        red[1][part][n] = bbp;
        __syncthreads();
        if (tid < 64) {
            csv[tid] = red[0][0][tid] + red[0][1][tid] + red[0][2][tid] + red[0][3][tid];
            bbv[tid] = red[1][0][tid] + red[1][1][tid] + red[1][2][tid] + red[1][3][tid]
                       + c1[tid];
        }
        return;
    }
    if (bid >= 4226 && bid < 4258) {  // zero LN1 stats (replay-safe)
        const int i = (bid - 4226) * 256 + tid;
        s1[i] = 0.0f;
        sq1[i] = 0.0f;
        return;
    }

    const float* in; bf16_t* out;
    const float* gvec = nullptr;
    int R, C, c0, r0;
    float scale = 1.0f;
    if (bid < 3072) {               // Wq/Wk/Wv [16][1024][64] -> per-head [64][1024]
        const int p = bid >> 10, r = bid & 1023;
        const int z = r >> 6, rem = r & 63;
        in  = (p == 0 ? Wq : p == 1 ? Wk : Wv) + z * 65536;
        out = WqkvT + p * 1048576 + z * 65536;
        R = 1024; C = 64;
        c0 = (rem & 1) * 32; r0 = (rem >> 1) * 32;
        if (p == 0) scale = QSCALE;
    } else if (bid < 4096) {        // Wo [1024][1024]
        const int r = bid - 3072;
        in = Wo; out = WoT; R = 1024; C = 1024;
        c0 = (r & 31) * 32; r0 = (r >> 5) * 32;
    } else if (bid < 4160) {        // W1 [1024][64], g1 folded per input row k
        const int r = bid - 4096;
        in = W1; out = W1gT; R = 1024; C = 64;
        c0 = (r & 1) * 32; r0 = (r >> 1) * 32;
        gvec = g1;
    } else {                        // W2 [64][1024]
        const int r = bid - 4160;
        in = W2; out = W2T; R = 64; C = 1024;
        c0 = (r & 31) * 32; r0 = (r >> 5) * 32;
    }

    {
        int rr = tid >> 3, c4 = (tid & 7) * 4;
        float sc = gvec ? gvec[r0 + rr] : scale;
        float4 v = *(const float4*)&in[(size_t)(r0 + rr) * C + c0 + c4];
        t[rr][c4 + 0] = v.x * sc;
        t[rr][c4 + 1] = v.y * sc;
        t[rr][c4 + 2] = v.z * sc;
        t[rr][c4 + 3] = v.w * sc;
    }
    __syncthreads();
    {
        int c = tid >> 3, r4 = (tid & 7) * 4;
        ushort4 o;
        o.x = bf16bits(t[r4 + 0][c]);
        o.y = bf16bits(t[r4 + 1][c]);
        o.z = bf16bits(t[r4 + 2][c]);
        o.w = bf16bits(t[r4 + 3][c]);
        *(ushort4*)(out + (size_t)(c0 + c) * R + r0 + r4) = o;
    }
}

// ---------------------------------------------------------------------------
// Row LayerNorm over 1024, bf16 in, f32 out (final LN2).
// ---------------------------------------------------------------------------
__global__ __launch_bounds__(256) void ln_kernel(
    const bf16_t* __restrict__ in, const float* __restrict__ g,
    const float* __restrict__ bta, float* __restrict__ out)
{
    const int row = blockIdx.x;
    const int tid = threadIdx.x;

    ushort4 xv = *(const ushort4*)(in + (size_t)row * E_ + tid * 4);
    float x0 = (float)__builtin_bit_cast(bf16_t, xv.x);
    float x1 = (float)__builtin_bit_cast(bf16_t, xv.y);
    float x2 = (float)__builtin_bit_cast(bf16_t, xv.z);
    float x3 = (float)__builtin_bit_cast(bf16_t, xv.w);
    float s  = x0 + x1 + x2 + x3;
    float sq = x0 * x0 + x1 * x1 + x2 * x2 + x3 * x3;
    #pragma unroll
    for (int off = 32; off > 0; off >>= 1) {
        s  += __shfl_down(s, off);
        sq += __shfl_down(sq, off);
    }
    __shared__ float ss[4], ssq[4];
    if ((tid & 63) == 0) { ss[tid >> 6] = s; ssq[tid >> 6] = sq; }
    __syncthreads();
    s  = ss[0] + ss[1] + ss[2] + ss[3];
    sq = ssq[0] + ssq[1] + ssq[2] + ssq[3];

    const float mean = s * (1.0f / E_);
    const float var  = sq * (1.0f / E_) - mean * mean;
    const float rstd = rsqrtf(var + 1e-5f);

    float4 gv = ((const float4*)g)[tid];
    float4 bv = ((const float4*)bta)[tid];
    float4 o;
    o.x = (x0 - mean) * rstd * gv.x + bv.x;
    o.y = (x1 - mean) * rstd * gv.y + bv.y;
    o.z = (x2 - mean) * rstd * gv.z + bv.z;
    o.w = (x3 - mean) * rstd * gv.w + bv.w;
    ((float4*)(out + (size_t)row * E_))[tid] = o;
}

// ---------------------------------------------------------------------------
extern "C" void kernel_launch(void* const* d_in, const int* in_sizes, int n_in,
                              void* d_out, int out_size, void* d_ws, size_t ws_size,
                              hipStream_t stream)
{
    const float* x    = (const float*)d_in[0];
    const int*   mask = (const int*)d_in[1];
    const float* Wq   = (const float*)d_in[2];
    const float* bq   = (const float*)d_in[3];
    const float* Wk   = (const float*)d_in[4];
    const float* bk   = (const float*)d_in[5];
    const float* Wv   = (const float*)d_in[6];
    const float* bv   = (const float*)d_in[7];
    const float* Wo   = (const float*)d_in[8];
    const float* bo   = (const float*)d_in[9];
    const float* g1   = (const float*)d_in[10];
    const float* b1   = (const float*)d_in[11];
    const float* W1   = (const float*)d_in[12];
    const float* c1   = (const float*)d_in[13];
    const float* W2   = (const float*)d_in[14];
    const float* c2   = (const float*)d_in[15];
    const float* g2   = (const float*)d_in[16];
    const float* b2   = (const float*)d_in[17];

    char* W = (char*)d_ws;                       // peak ~92.7 MB
    bf16_t* xb    = (bf16_t*)(W + 0);            // 16 MB
    bf16_t* WqkvT = (bf16_t*)(W + 16777216);     //  6 MB [3][1024 n][1024 k]
    bf16_t* WoT   = (bf16_t*)(W + 23068672);     //  2 MB
    bf16_t* W1gT  = (bf16_t*)(W + 25165824);     //  128K (g1-folded)
    bf16_t* W2T   = (bf16_t*)(W + 25296896);     //  128K
    bf16_t* qbuf  = (bf16_t*)(W + 25427968);     // 16 MB [b,s,h,d]
    bf16_t* kbuf  = (bf16_t*)(W + 42205184);     // 16 MB [b][ci][h,d] compact
    bf16_t* vtc   = (bf16_t*)(W + 58982400);     // 16 MB [bh][d][ci] compact
    bf16_t* ctx   = (bf16_t*)(W + 75759616);     // 16 MB
    bf16_t* t1b   = (bf16_t*)(W + 25427968);     // over qbuf (dead after attn)
    bf16_t* f1b   = (bf16_t*)(W + 0);            // over xb (dead after GEMMs)
    bf16_t* f2b   = (bf16_t*)(W + 58982400);     // over vtc (dead after attn)
    int*    sidx  = (int*)(W + 92536832);        // 32 KB
    int*    nkv   = (int*)(W + 92569600);        // 64 B  (nkv[4] = nab)
    float*  bqs   = (float*)(W + 92569664);      // 4 KB
    int*    bmap  = (int*)(W + 92573760);        // 256 B
    float*  csv   = (float*)(W + 92574016);      // 256 B
    float*  bbv   = (float*)(W + 92574272);      // 256 B
    float*  s1    = (float*)(W + 92574528);      // 32 KB LN1 row sums
    float*  sq1   = (float*)(W + 92607296);      // 32 KB LN1 row sumsq
    float*  out   = (float*)d_out;

    // fused prep (scales folded; g1 into W1; cs/bb; zero LN1 stats)
    prep_all<<<8354, 256, 0, stream>>>(x, xb, Wq, Wk, Wv, WqkvT,
                                       Wo, WoT, W1, W1gT, W2, W2T, bq, bqs,
                                       g1, b1, c1, csv, bbv, s1, sq1);

    // mask scan -> sidx / nkv / bmap / nab
    compact_mask<<<1, 256, 0, stream>>>(mask, sidx, nkv, bmap);

    // Q projection [8192 x 1024 x 1024] -> qbuf
    gemm_bf16<128, 128, 0><<<dim3(8, 64), 256, 0, stream>>>(
        xb, WqkvT, qbuf, nullptr, nullptr, bqs, nullptr, nullptr, nullptr,
        nullptr, nullptr, nullptr, M_, 1024, 1024);

    // KV projection over compacted rows (single-buffer, supertile mapping)
    gemm_bf16<128, 128, 2><<<dim3(16, 64), 256, 0, stream>>>(
        xb, WqkvT + (1 << 20), nullptr, kbuf, vtc, bk, bv, nullptr, nullptr,
        sidx, nkv, bmap, M_, 2048, 1024);

    // attention over compacted keys (8 waves, QBLK=256, counted-vmcnt)
    attn_mfma<<<dim3(512), 512, 0, stream>>>(qbuf, kbuf, vtc, nkv, ctx);

    // output projection -> bf16 t1 + LN1 row stats (atomic)
    gemm_bf16<128, 128, 4><<<dim3(8, 64), 256, 0, stream>>>(
        ctx, WoT, t1b, nullptr, nullptr, bo, nullptr, s1, sq1,
        nullptr, nullptr, nullptr, M_, 1024, 1024);

    // LN1-fused FFN1 (N=64) + exact GELU -> bf16
    gemm_bf16<32, 64, 6><<<dim3(1, 256), 256, 0, stream>>>(
        t1b, W1gT, f1b, nullptr, nullptr, csv, bbv, s1, sq1,
        nullptr, nullptr, nullptr, M_, 64, 1024);

    // FFN2 (K=64) -> bf16
    gemm_bf16<128, 128, 0><<<dim3(8, 64), 256, 0, stream>>>(
        f1b, W2T, f2b, nullptr, nullptr, c2, nullptr, nullptr, nullptr,
        nullptr, nullptr, nullptr, M_, 1024, 64);

    ln_kernel<<<8192, 256, 0, stream>>>(f2b, g2, b2, out);
}

// Round 25
// 180.870 us; speedup vs baseline: 1.0324x; 1.0324x over previous
//
#include <hip/hip_runtime.h>
#include <math.h>

#define B_ 4
#define S_ 2048
#define E_ 1024
#define H_ 16
#define D_ 64
#define M_ (B_*S_)
// 1/sqrt(2048) * log2(e): scale folded into Wq/bq so softmax uses exp2 directly
#define QSCALE (0.022097086912079608f * 1.4426950408889634f)

typedef __bf16 bf16_t;
typedef __bf16 bf16x8 __attribute__((ext_vector_type(8)));
typedef float  f32x4  __attribute__((ext_vector_type(4)));

// async global->LDS, 16B per lane. LDS dest must be linear (base + lane*16).
__device__ __forceinline__ void gload_lds16(const void* g, void* l) {
    __builtin_amdgcn_global_load_lds(
        (const __attribute__((address_space(1))) void*)g,
        (__attribute__((address_space(3))) void*)l, 16, 0, 0);
}
__device__ __forceinline__ bf16x8 ldsx8(const void* p) {
    return __builtin_bit_cast(bf16x8, *(const uint4*)p);
}
__device__ __forceinline__ unsigned short bf16bits(float x) {
    return __builtin_bit_cast(unsigned short, (bf16_t)x);
}
// counted waitcnt: allow N newest vector-mem ops to stay in flight
template<int N> __device__ __forceinline__ void waitv() {
    if constexpr (N == 8)      asm volatile("s_waitcnt vmcnt(8) lgkmcnt(0)" ::: "memory");
    else if constexpr (N == 4) asm volatile("s_waitcnt vmcnt(4) lgkmcnt(0)" ::: "memory");
    else if constexpr (N == 3) asm volatile("s_waitcnt vmcnt(3) lgkmcnt(0)" ::: "memory");
    else if constexpr (N == 2) asm volatile("s_waitcnt vmcnt(2) lgkmcnt(0)" ::: "memory");
    else                       asm volatile("s_waitcnt vmcnt(0) lgkmcnt(0)" ::: "memory");
}
// swizzle for K-tile QK^T A-frag read rows {32c + 8a + 4kf + b}: f = (b + 2a) & 7
__device__ __forceinline__ int fk(int row) { return ((row & 3) + 2 * ((row >> 3) & 3)) & 7; }

// ---------------------------------------------------------------------------
// bf16 MFMA GEMM, C = A[M,K] x Bt[N,K]^T. BK=64.
// MODE 0/1: LDS double-buffered (64KB, 2 blocks/CU), counted-vmcnt barriers —
//   right for grids <= 512 blocks (one residency wave).
// MODE 2: compacted KV projection. SINGLE-buffer 32KB LDS (4 blocks/CU ->
//   all ~576 alive blocks resident in ONE scheduling wave). Supertile mapping
//   (XCD-balanced + A-panel-reusing); direct-store epilogue.
//   K -> ob1[b][ci][nn]; V -> ob2[bh][d][ci] (4 consecutive ci).
// ---------------------------------------------------------------------------
template<int BM, int BN, int MODE>
__global__ __launch_bounds__(256) void gemm_bf16(
    const bf16_t* __restrict__ A, const bf16_t* __restrict__ Bt,
    bf16_t* __restrict__ ob0, bf16_t* __restrict__ ob1, bf16_t* __restrict__ ob2,
    const float* __restrict__ bias0, const float* __restrict__ bias1,
    const int* __restrict__ sidx, const int* __restrict__ nkv,
    const int* __restrict__ bmap,
    int M, int N, int K)
{
    constexpr int FM = BM / 32, FN = BN / 32;
    constexpr int NL = BM / 32 + BN / 32;    // gload_lds per thread per K-step
    constexpr int NBUF = (MODE == 2) ? 1 : 2;
    __shared__ bf16_t As[NBUF][BM * 64];
    __shared__ bf16_t Bs[NBUF][BN * 64];

    const int tid = threadIdx.x;
    const int w   = tid >> 6;
    const int wr  = w >> 1, wc = w & 1;
    const int lr  = tid & 15;
    const int lg  = (tid >> 4) & 3;

    int bm, bn;
    if constexpr (MODE == 2) {
        const int flat = blockIdx.y * gridDim.x + blockIdx.x;   // [0,1024)
        const int nab = nkv[4];
        const int st = flat >> 7, wfl = flat & 127;
        const int ab = st * 8 + (wfl & 7);
        if (ab >= nab) return;
        const int col = wfl >> 3;
        const int ent = bmap[ab];
        bm = ((ent >> 8) << 11) + (ent & 255) * BM;   // [b][ci] row base
        bn = col * BN;
    } else {
        // XCD-bijective block swizzle: 8 contiguous chunks, one per XCD
        const int nwg = gridDim.x * gridDim.y;
        int bidf = blockIdx.y * gridDim.x + blockIdx.x;
        bidf = (bidf & 7) * (nwg >> 3) + (bidf >> 3);
        bm = (bidf / gridDim.x) * BM;
        bn = (bidf % gridDim.x) * BN;
    }

    // A-row mapping (MODE 2: gathered via sidx)
    int arow[FM];
    if constexpr (MODE == 2) {
        const int b2 = bm >> 11, rbase = bm & 2047;
        #pragma unroll
        for (int i = 0; i < FM; ++i) {
            const int row = (i * 256 + tid) >> 3;
            arow[i] = (b2 << 11) + sidx[(b2 << 11) + rbase + row];
        }
    } else {
        #pragma unroll
        for (int i = 0; i < FM; ++i)
            arow[i] = bm + ((i * 256 + tid) >> 3);
    }

    f32x4 acc[FM][FN] = {};

    auto STAGE = [&](int buf, int kk) {
        #pragma unroll
        for (int i = 0; i < BM / 32; ++i) {
            int idx = i * 256 + tid;
            int row = idx >> 3, slot = idx & 7;
            gload_lds16(A + (size_t)arow[i] * K + kk + (slot ^ (row & 7)) * 8,
                        (char*)As[buf] + idx * 16);
        }
        #pragma unroll
        for (int i = 0; i < BN / 32; ++i) {
            int idx = i * 256 + tid;
            int row = idx >> 3, slot = idx & 7;
            gload_lds16(Bt + (size_t)(bn + row) * K + kk + (slot ^ (row & 7)) * 8,
                        (char*)Bs[buf] + idx * 16);
        }
    };

    auto COMPUTE = [&](int buf) {
        #pragma unroll
        for (int h = 0; h < 2; ++h) {
            bf16x8 af[FM], bfr[FN];
            #pragma unroll
            for (int m = 0; m < FM; ++m) {
                int row = wr * (BM / 2) + m * 16 + lr;
                af[m] = ldsx8((char*)As[buf] + row * 128 + (((4 * h + lg) ^ (row & 7)) << 4));
            }
            #pragma unroll
            for (int n = 0; n < FN; ++n) {
                int col = wc * (BN / 2) + n * 16 + lr;
                bfr[n] = ldsx8((char*)Bs[buf] + col * 128 + (((4 * h + lg) ^ (col & 7)) << 4));
            }
            #pragma unroll
            for (int m = 0; m < FM; ++m)
                #pragma unroll
                for (int n = 0; n < FN; ++n)
                    acc[m][n] = __builtin_amdgcn_mfma_f32_16x16x32_bf16(
                        af[m], bfr[n], acc[m][n], 0, 0, 0);
        }
    };

    if constexpr (NBUF == 1) {
        // single-buffer sync loop: 4 blocks/CU residency
        for (int kk = 0; kk < K; kk += 64) {
            __syncthreads();
            STAGE(0, kk);
            __syncthreads();
            COMPUTE(0);
        }
    } else {
        STAGE(0, 0);
        int cur = 0;
        for (int kk = 0; kk < K; kk += 64) {
            if (kk + 64 < K) {
                STAGE(cur ^ 1, kk + 64);
                waitv<NL>();
            } else {
                waitv<0>();
            }
            __builtin_amdgcn_s_barrier();
            COMPUTE(cur);
            __builtin_amdgcn_s_barrier();
            cur ^= 1;
        }
    }

    #pragma unroll
    for (int n = 0; n < FN; ++n) {
        const int gcol = bn + wc * (BN / 2) + n * 16 + lr;
        if constexpr (MODE == 2) {
            const int p = gcol >> 10, nn = gcol & 1023;
            const int b2 = bm >> 11;
            const float bvl = p ? bias1[nn] : bias0[nn];
            #pragma unroll
            for (int m = 0; m < FM; ++m) {
                const int ci0 = (bm & 2047) + wr * (BM / 2) + m * 16 + lg * 4;
                if (p) {    // V^T: vtc[((b*1024 + nn) << 11) + ci], 4 consecutive ci
                    ushort4 o;
                    o.x = bf16bits(acc[m][n][0] + bvl);
                    o.y = bf16bits(acc[m][n][1] + bvl);
                    o.z = bf16bits(acc[m][n][2] + bvl);
                    o.w = bf16bits(acc[m][n][3] + bvl);
                    *(ushort4*)(ob2 + ((((size_t)b2 << 10) + nn) << 11) + ci0) = o;
                } else {    // K: kbuf[((b<<11) + ci) << 10 + nn]
                    #pragma unroll
                    for (int r = 0; r < 4; ++r)
                        ob1[((size_t)((b2 << 11) + ci0 + r) << 10) + nn] =
                            (bf16_t)(acc[m][n][r] + bvl);
                }
            }
        } else {
            const float bvl = bias0[gcol];
            #pragma unroll
            for (int m = 0; m < FM; ++m)
                #pragma unroll
                for (int r = 0; r < 4; ++r) {
                    const int grow = bm + wr * (BM / 2) + m * 16 + lg * 4 + r;
                    float v = acc[m][n][r] + bvl;
                    if constexpr (MODE == 1)
                        v = 0.5f * v * (1.0f + erff(v * 0.70710678118654752f));
                    ob0[(size_t)grow * N + gcol] = (bf16_t)v;
                }
        }
    }
}

// ---------------------------------------------------------------------------
// Mask compaction (single block): scan -> sidx (pad 0 to 128-mult); nkv[b];
// bmap[ab] = (b<<8)|rb for alive 128-row blocks; nkv[4] = nab.
// ---------------------------------------------------------------------------
__global__ __launch_bounds__(256) void compact_mask(
    const int* __restrict__ mask, int* __restrict__ sidx, int* __restrict__ nkv,
    int* __restrict__ bmap)
{
    __shared__ int wsum[4];
    __shared__ int nkp_s[4];
    const int tid = threadIdx.x;
    const int lane = tid & 63, wv = tid >> 6;
    const int base = tid * 8;

    for (int b = 0; b < 4; ++b) {
        int m[8], loc[8];
        int cnt = 0;
        #pragma unroll
        for (int j = 0; j < 8; ++j) {
            m[j] = mask[b * S_ + base + j];
            loc[j] = cnt;
            cnt += (m[j] != 0);
        }
        int incl = cnt;
        #pragma unroll
        for (int off = 1; off < 64; off <<= 1) {
            int t = __shfl_up(incl, off);
            if (lane >= off) incl += t;
        }
        if (lane == 63) wsum[wv] = incl;
        const int excl_lane = incl - cnt;
        __syncthreads();
        int wbase = 0;
        for (int i = 0; i < wv; ++i) wbase += wsum[i];
        const int total = wsum[0] + wsum[1] + wsum[2] + wsum[3];
        if (tid == 0) { nkv[b] = total; nkp_s[b] = (total + 127) & ~127; }
        const int tbase = wbase + excl_lane;
        #pragma unroll
        for (int j = 0; j < 8; ++j)
            if (m[j]) sidx[b * S_ + tbase + loc[j]] = base + j;
        const int nkp = (total + 127) & ~127;
        for (int c = total + tid; c < nkp; c += 256)
            sidx[b * S_ + c] = 0;
        __syncthreads();
    }

    if (tid == 0) {
        int idx = 0;
        for (int b = 0; b < 4; ++b)
            for (int rb = 0; rb < (nkp_s[b] >> 7); ++rb)
                bmap[idx++] = (b << 8) | rb;
        nkv[4] = idx;
    }
}

// ---------------------------------------------------------------------------
// MFMA flash attention over COMPACTED keys. 8 waves x 32 q-rows = QBLK 256,
// grid 512 (64 bh x 8 q-blocks). TRIPLE-buffer, 2-tiles-ahead counted
// pipeline: stage t+2, waitv<4> (tiles t+1,t+2 stay in flight, only tile t
// drained). LDS 48KB (residency unchanged: grid 512 = 2 blocks/CU).
// Zero-shuffle P path; mask-as-C-init; L via ones-row MFMA; exp2-domain
// scores. 8 bh per XCD.
// ---------------------------------------------------------------------------
__global__ __launch_bounds__(512) void attn_mfma(
    const bf16_t* __restrict__ qg, const bf16_t* __restrict__ kg,
    const bf16_t* __restrict__ vg, const int* __restrict__ nkv,
    bf16_t* __restrict__ ctx)
{
    __shared__ bf16_t ks[3][64 * 64];   // [key][d] 128B rows, fk-swizzled
    __shared__ bf16_t vts[3][64 * 64];  // [d][key] 128B rows, row&7-swizzled

    const int tid = threadIdx.x;
    const int w   = tid >> 6;            // 8 waves
    const int lr  = tid & 15;
    const int lg  = (tid >> 4) & 3;

    const int bid = blockIdx.x;
    const int xcd = bid & 7, kidx = bid >> 3;        // kidx in [0,64)
    const int bh  = xcd * 8 + (kidx >> 3);           // 8 bh per XCD
    const int xq  = kidx & 7;                        // 8 q-blocks of 256
    const int b   = bh >> 4, h = bh & 15;
    const int q0w = xq * 256 + w * 32;               // wave owns 32 q-rows

    const int nk = nkv[b];
    const int ntiles = (nk + 63) >> 6;
    const bool hastail = (nk & 63) != 0;

    bf16x8 aq[2][2];
    #pragma unroll
    for (int f = 0; f < 2; ++f) {
        const bf16_t* qp = qg + ((size_t)(b * S_ + q0w + f * 16 + lr) << 10) + h * 64 + lg * 8;
        aq[f][0] = ldsx8(qp);
        aq[f][1] = ldsx8(qp + 32);
    }

    bf16x8 onesf;
    {
        bf16_t o1 = (bf16_t)((lr == 0) ? 1.0f : 0.0f);
        #pragma unroll
        for (int j = 0; j < 8; ++j) onesf[j] = o1;
    }

    int koff[2][2][2], voff[2][4];
    #pragma unroll
    for (int c = 0; c < 2; ++c) {
        #pragma unroll
        for (int kf1 = 0; kf1 < 2; ++kf1) {
            const int row = c * 32 + 8 * (lr >> 2) + 4 * kf1 + (lr & 3);
            const int f = fk(row);
            koff[c][kf1][0] = row * 128 + ((lg ^ f) << 4);
            koff[c][kf1][1] = row * 128 + (((4 + lg) ^ f) << 4);
        }
        #pragma unroll
        for (int n = 0; n < 4; ++n) {
            const int rowv = n * 16 + lr;
            voff[c][n] = rowv * 128 + (((4 * c + lg) ^ (rowv & 7)) << 4);
        }
    }

    const int srow = tid >> 3, sslot = tid & 7;      // srow in [0,64)
    const bf16_t* kptr = kg + ((size_t)((b << 11) + srow) << 10) + h * 64
                            + (sslot ^ fk(srow)) * 8;
    const bf16_t* vptr = vg + (((size_t)bh * 64 + srow) << 11)
                            + (sslot ^ (srow & 7)) * 8;
    char* kdst = (char*)ks + tid * 16;
    char* vdst = (char*)vts + tid * 16;

    f32x4 accO[2][4] = {};
    f32x4 accL[2] = {};

    auto STAGE = [&](int buf) {
        const int nb = buf << 13;
        gload_lds16(kptr, kdst + nb);
        gload_lds16(vptr, vdst + nb);
        kptr += (size_t)64 << 10;
        vptr += 64;
    };

    auto COMPUTE = [&](int buf, int t0, bool tl) {
        const char* ksb = (const char*)ks + (buf << 13);
        const char* vsb = (const char*)vts + (buf << 13);
        #pragma unroll
        for (int c = 0; c < 2; ++c) {
            unsigned int pw0[4], pw1[4];
            #pragma unroll
            for (int kf1 = 0; kf1 < 2; ++kf1) {
                bf16x8 a0 = ldsx8(ksb + koff[c][kf1][0]);
                bf16x8 a1 = ldsx8(ksb + koff[c][kf1][1]);
                f32x4 z0 = {}, z1 = {};
                if (tl) {
                    const int keyb = t0 + c * 32 + 8 * lg + 4 * kf1;
                    f32x4 bias;
                    #pragma unroll
                    for (int r = 0; r < 4; ++r)
                        bias[r] = (keyb + r < nk) ? 0.0f : -1.0e9f;
                    z0 = bias; z1 = bias;
                }
                __builtin_amdgcn_s_setprio(1);
                z0 = __builtin_amdgcn_mfma_f32_16x16x32_bf16(a0, aq[0][0], z0, 0, 0, 0);
                z0 = __builtin_amdgcn_mfma_f32_16x16x32_bf16(a1, aq[0][1], z0, 0, 0, 0);
                z1 = __builtin_amdgcn_mfma_f32_16x16x32_bf16(a0, aq[1][0], z1, 0, 0, 0);
                z1 = __builtin_amdgcn_mfma_f32_16x16x32_bf16(a1, aq[1][1], z1, 0, 0, 0);
                __builtin_amdgcn_s_setprio(0);
                const float p00 = __builtin_amdgcn_exp2f(z0[0]);
                const float p01 = __builtin_amdgcn_exp2f(z0[1]);
                const float p02 = __builtin_amdgcn_exp2f(z0[2]);
                const float p03 = __builtin_amdgcn_exp2f(z0[3]);
                const float p10 = __builtin_amdgcn_exp2f(z1[0]);
                const float p11 = __builtin_amdgcn_exp2f(z1[1]);
                const float p12 = __builtin_amdgcn_exp2f(z1[2]);
                const float p13 = __builtin_amdgcn_exp2f(z1[3]);
                pw0[2 * kf1]     = bf16bits(p00) | ((unsigned)bf16bits(p01) << 16);
                pw0[2 * kf1 + 1] = bf16bits(p02) | ((unsigned)bf16bits(p03) << 16);
                pw1[2 * kf1]     = bf16bits(p10) | ((unsigned)bf16bits(p11) << 16);
                pw1[2 * kf1 + 1] = bf16bits(p12) | ((unsigned)bf16bits(p13) << 16);
            }
            uint4 pk0 = {pw0[0], pw0[1], pw0[2], pw0[3]};
            uint4 pk1 = {pw1[0], pw1[1], pw1[2], pw1[3]};
            const bf16x8 pa0 = __builtin_bit_cast(bf16x8, pk0);
            const bf16x8 pa1 = __builtin_bit_cast(bf16x8, pk1);

            __builtin_amdgcn_s_setprio(1);
            #pragma unroll
            for (int n = 0; n < 4; ++n) {
                bf16x8 av = ldsx8(vsb + voff[c][n]);
                accO[0][n] = __builtin_amdgcn_mfma_f32_16x16x32_bf16(av, pa0, accO[0][n], 0, 0, 0);
                accO[1][n] = __builtin_amdgcn_mfma_f32_16x16x32_bf16(av, pa1, accO[1][n], 0, 0, 0);
            }
            accL[0] = __builtin_amdgcn_mfma_f32_16x16x32_bf16(onesf, pa0, accL[0], 0, 0, 0);
            accL[1] = __builtin_amdgcn_mfma_f32_16x16x32_bf16(onesf, pa1, accL[1], 0, 0, 0);
            __builtin_amdgcn_s_setprio(0);
        }
    };

    // 3-deep pipeline: prologue stages tiles 0,1; loop stages t+2, waits tile t
    STAGE(0);
    if (ntiles > 1) STAGE(1);
    int cur = 0, stg = 2;
    for (int t = 0; t < ntiles; ++t) {
        if (t + 2 < ntiles) {
            STAGE(stg);
            stg = (stg == 2) ? 0 : stg + 1;
            waitv<4>();
        } else if (t + 1 < ntiles) {
            waitv<2>();
        } else {
            waitv<0>();
        }
        __builtin_amdgcn_s_barrier();
        COMPUTE(cur, t * 64, hastail && (t == ntiles - 1));
        __builtin_amdgcn_s_barrier();
        cur = (cur == 2) ? 0 : cur + 1;
    }

    #pragma unroll
    for (int f = 0; f < 2; ++f) {
        const float inv = 1.0f / __shfl(accL[f][0], lr);
        bf16_t* obase = ctx + ((size_t)(b * S_ + q0w + f * 16 + lr) << 10) + h * 64;
        #pragma unroll
        for (int n = 0; n < 4; ++n) {
            ushort4 o;
            o.x = bf16bits(accO[f][n][0] * inv);
            o.y = bf16bits(accO[f][n][1] * inv);
            o.z = bf16bits(accO[f][n][2] * inv);
            o.w = bf16bits(accO[f][n][3] * inv);
            *(ushort4*)(obase + n * 16 + lg * 4) = o;
        }
    }
}

// ---------------------------------------------------------------------------
// Fused prep: x cast + all 5 weight transpose/converts + bqs = bq*QSCALE.
// ---------------------------------------------------------------------------
__global__ __launch_bounds__(256) void prep_all(
    const float* __restrict__ x, bf16_t* __restrict__ xb,
    const float* __restrict__ Wq, const float* __restrict__ Wk,
    const float* __restrict__ Wv, bf16_t* __restrict__ WqkvT,
    const float* __restrict__ Wo, bf16_t* __restrict__ WoT,
    const float* __restrict__ W1, bf16_t* __restrict__ W1T,
    const float* __restrict__ W2, bf16_t* __restrict__ W2T,
    const float* __restrict__ bq, float* __restrict__ bqs)
{
    __shared__ float t[32][33];
    const int tid = threadIdx.x;
    int bid = blockIdx.x;

    if (bid < 4096) {               // x f32 -> bf16, 8 per thread
        int i = bid * 256 + tid;
        float4 a = ((const float4*)x)[i * 2];
        float4 b = ((const float4*)x)[i * 2 + 1];
        unsigned int p0 = bf16bits(a.x) | ((unsigned)bf16bits(a.y) << 16);
        unsigned int p1 = bf16bits(a.z) | ((unsigned)bf16bits(a.w) << 16);
        unsigned int p2 = bf16bits(b.x) | ((unsigned)bf16bits(b.y) << 16);
        unsigned int p3 = bf16bits(b.z) | ((unsigned)bf16bits(b.w) << 16);
        uint4 o = {p0, p1, p2, p3};
        ((uint4*)xb)[i] = o;
        return;
    }
    bid -= 4096;

    if (bid == 4224) {              // bqs = bq * QSCALE
        #pragma unroll
        for (int j = 0; j < 4; ++j)
            bqs[tid * 4 + j] = bq[tid * 4 + j] * QSCALE;
        return;
    }

    const float* in; bf16_t* out;
    int R, C, c0, r0;
    float scale = 1.0f;
    if (bid < 3072) {               // Wq/Wk/Wv [16][1024][64] -> per-head [64][1024]
        const int p = bid >> 10, r = bid & 1023;
        const int z = r >> 6, rem = r & 63;
        in  = (p == 0 ? Wq : p == 1 ? Wk : Wv) + z * 65536;
        out = WqkvT + p * 1048576 + z * 65536;
        R = 1024; C = 64;
        c0 = (rem & 1) * 32; r0 = (rem >> 1) * 32;
        if (p == 0) scale = QSCALE;
    } else if (bid < 4096) {        // Wo [1024][1024]
        const int r = bid - 3072;
        in = Wo; out = WoT; R = 1024; C = 1024;
        c0 = (r & 31) * 32; r0 = (r >> 5) * 32;
    } else if (bid < 4160) {        // W1 [1024][64]
        const int r = bid - 4096;
        in = W1; out = W1T; R = 1024; C = 64;
        c0 = (r & 1) * 32; r0 = (r >> 1) * 32;
    } else {                        // W2 [64][1024]
        const int r = bid - 4160;
        in = W2; out = W2T; R = 64; C = 1024;
        c0 = (r & 31) * 32; r0 = (r >> 5) * 32;
    }

    {
        int rr = tid >> 3, c4 = (tid & 7) * 4;
        float4 v = *(const float4*)&in[(size_t)(r0 + rr) * C + c0 + c4];
        t[rr][c4 + 0] = v.x * scale;
        t[rr][c4 + 1] = v.y * scale;
        t[rr][c4 + 2] = v.z * scale;
        t[rr][c4 + 3] = v.w * scale;
    }
    __syncthreads();
    {
        int c = tid >> 3, r4 = (tid & 7) * 4;
        ushort4 o;
        o.x = bf16bits(t[r4 + 0][c]);
        o.y = bf16bits(t[r4 + 1][c]);
        o.z = bf16bits(t[r4 + 2][c]);
        o.w = bf16bits(t[r4 + 3][c]);
        *(ushort4*)(out + (size_t)(c0 + c) * R + r0 + r4) = o;
    }
}

// ---------------------------------------------------------------------------
// Row LayerNorm over 1024. InT: float or bf16; OutT: float or bf16.
// ---------------------------------------------------------------------------
template<typename InT, typename OutT>
__global__ __launch_bounds__(256) void ln_kernel(
    const InT* __restrict__ in, const float* __restrict__ g,
    const float* __restrict__ bta, OutT* __restrict__ out)
{
    const int row = blockIdx.x;
    const int tid = threadIdx.x;

    float x0, x1, x2, x3;
    if constexpr (sizeof(InT) == 4) {
        float4 xv = ((const float4*)(in + (size_t)row * E_))[tid];
        x0 = xv.x; x1 = xv.y; x2 = xv.z; x3 = xv.w;
    } else {
        ushort4 xv = *(const ushort4*)((const bf16_t*)in + (size_t)row * E_ + tid * 4);
        x0 = (float)__builtin_bit_cast(bf16_t, xv.x);
        x1 = (float)__builtin_bit_cast(bf16_t, xv.y);
        x2 = (float)__builtin_bit_cast(bf16_t, xv.z);
        x3 = (float)__builtin_bit_cast(bf16_t, xv.w);
    }
    float s  = x0 + x1 + x2 + x3;
    float sq = x0 * x0 + x1 * x1 + x2 * x2 + x3 * x3;
    #pragma unroll
    for (int off = 32; off > 0; off >>= 1) {
        s  += __shfl_down(s, off);
        sq += __shfl_down(sq, off);
    }
    __shared__ float ss[4], ssq[4];
    if ((tid & 63) == 0) { ss[tid >> 6] = s; ssq[tid >> 6] = sq; }
    __syncthreads();
    s  = ss[0] + ss[1] + ss[2] + ss[3];
    sq = ssq[0] + ssq[1] + ssq[2] + ssq[3];

    const float mean = s * (1.0f / E_);
    const float var  = sq * (1.0f / E_) - mean * mean;
    const float rstd = rsqrtf(var + 1e-5f);

    float4 gv = ((const float4*)g)[tid];
    float4 bv = ((const float4*)bta)[tid];
    float o0 = (x0 - mean) * rstd * gv.x + bv.x;
    float o1 = (x1 - mean) * rstd * gv.y + bv.y;
    float o2 = (x2 - mean) * rstd * gv.z + bv.z;
    float o3 = (x3 - mean) * rstd * gv.w + bv.w;
    if constexpr (sizeof(OutT) == 4) {
        float4 o = {o0, o1, o2, o3};
        ((float4*)((float*)out + (size_t)row * E_))[tid] = o;
    } else {
        ushort4 o;
        o.x = bf16bits(o0); o.y = bf16bits(o1);
        o.z = bf16bits(o2); o.w = bf16bits(o3);
        *(ushort4*)((bf16_t*)out + (size_t)row * E_ + tid * 4) = o;
    }
}

// ---------------------------------------------------------------------------
extern "C" void kernel_launch(void* const* d_in, const int* in_sizes, int n_in,
                              void* d_out, int out_size, void* d_ws, size_t ws_size,
                              hipStream_t stream)
{
    const float* x    = (const float*)d_in[0];
    const int*   mask = (const int*)d_in[1];
    const float* Wq   = (const float*)d_in[2];
    const float* bq   = (const float*)d_in[3];
    const float* Wk   = (const float*)d_in[4];
    const float* bk   = (const float*)d_in[5];
    const float* Wv   = (const float*)d_in[6];
    const float* bv   = (const float*)d_in[7];
    const float* Wo   = (const float*)d_in[8];
    const float* bo   = (const float*)d_in[9];
    const float* g1   = (const float*)d_in[10];
    const float* b1   = (const float*)d_in[11];
    const float* W1   = (const float*)d_in[12];
    const float* c1   = (const float*)d_in[13];
    const float* W2   = (const float*)d_in[14];
    const float* c2   = (const float*)d_in[15];
    const float* g2   = (const float*)d_in[16];
    const float* b2   = (const float*)d_in[17];

    char* W = (char*)d_ws;                       // peak ~92.6 MB
    bf16_t* xb    = (bf16_t*)(W + 0);            // 16 MB
    bf16_t* WqkvT = (bf16_t*)(W + 16777216);     //  6 MB [3][1024 n][1024 k]
    bf16_t* WoT   = (bf16_t*)(W + 23068672);     //  2 MB
    bf16_t* W1T   = (bf16_t*)(W + 25165824);     //  128K
    bf16_t* W2T   = (bf16_t*)(W + 25296896);     //  128K
    bf16_t* qbuf  = (bf16_t*)(W + 25427968);     // 16 MB [b,s,h,d]
    bf16_t* kbuf  = (bf16_t*)(W + 42205184);     // 16 MB [b][ci][h,d] compact
    bf16_t* vtc   = (bf16_t*)(W + 58982400);     // 16 MB [bh][d][ci] compact
    bf16_t* ctx   = (bf16_t*)(W + 75759616);     // 16 MB
    bf16_t* t1b   = (bf16_t*)(W + 25427968);     // over qbuf (dead after attn)
    bf16_t* hb    = (bf16_t*)(W + 42205184);     // over kbuf (dead after attn)
    bf16_t* f1b   = (bf16_t*)(W + 0);            // over xb (dead after GEMMs)
    bf16_t* f2b   = (bf16_t*)(W + 58982400);     // over vtc (dead after attn)
    int*    sidx  = (int*)(W + 92536832);        // 32 KB
    int*    nkv   = (int*)(W + 92569600);        // 64 B  (nkv[4] = nab)
    float*  bqs   = (float*)(W + 92569664);      // 4 KB
    int*    bmap  = (int*)(W + 92573760);        // 256 B
    float*  out   = (float*)d_out;

    // fused prep (1/sqrt(S)*log2e folded into Wq and bqs)
    prep_all<<<8321, 256, 0, stream>>>(x, xb, Wq, Wk, Wv, WqkvT,
                                       Wo, WoT, W1, W1T, W2, W2T, bq, bqs);

    // mask scan -> sidx / nkv / bmap / nab
    compact_mask<<<1, 256, 0, stream>>>(mask, sidx, nkv, bmap);

    // Q projection [8192 x 1024 x 1024] -> qbuf
    gemm_bf16<128, 128, 0><<<dim3(8, 64), 256, 0, stream>>>(
        xb, WqkvT, qbuf, nullptr, nullptr, bqs, nullptr, nullptr, nullptr,
        nullptr, M_, 1024, 1024);

    // KV projection over compacted rows (single-buffer, supertile mapping)
    gemm_bf16<128, 128, 2><<<dim3(16, 64), 256, 0, stream>>>(
        xb, WqkvT + (1 << 20), nullptr, kbuf, vtc, bk, bv, sidx, nkv,
        bmap, M_, 2048, 1024);

    // attention over compacted keys (8 waves, QBLK=256, 3-deep pipeline)
    attn_mfma<<<dim3(512), 512, 0, stream>>>(qbuf, kbuf, vtc, nkv, ctx);

    // output projection -> bf16 t1
    gemm_bf16<128, 128, 0><<<dim3(8, 64), 256, 0, stream>>>(
        ctx, WoT, t1b, nullptr, nullptr, bo, nullptr, nullptr, nullptr,
        nullptr, M_, 1024, 1024);

    ln_kernel<bf16_t, bf16_t><<<8192, 256, 0, stream>>>(t1b, g1, b1, hb);

    // FFN1 (N=64) + exact GELU -> bf16
    gemm_bf16<32, 64, 1><<<dim3(1, 256), 256, 0, stream>>>(
        hb, W1T, f1b, nullptr, nullptr, c1, nullptr, nullptr, nullptr,
        nullptr, M_, 64, 1024);

    // FFN2 (K=64) -> bf16
    gemm_bf16<128, 128, 0><<<dim3(8, 64), 256, 0, stream>>>(
        f1b, W2T, f2b, nullptr, nullptr, c2, nullptr, nullptr, nullptr,
        nullptr, M_, 1024, 64);

    ln_kernel<bf16_t, float><<<8192, 256, 0, stream>>>(f2b, g2, b2, out);
}